// Round 12
// baseline (41.480 us; speedup 1.0000x reference)
//
#include <hip/hip_runtime.h>
#include <hip/hip_bf16.h>
#include <math.h>

#define BATCH    4
#define NPTS     8192
#define NSIDE    (BATCH * NPTS)     // 32768 points per side
#define NMINS    (2 * NSIDE)        // 65536 per-query mins
#define THREADS  256
#define INF_BITS 0x7F800000u

// ws layout: [0,1M) preds FB records (32768 x 32B); [1M,1.25M) uint mins; [1.25M,+16) u64 acc
#define WS_MIN_OFF (1ull * NSIDE * 32)
#define WS_ACC_OFF (WS_MIN_OFF + (size_t)NMINS * 4)

typedef __attribute__((ext_vector_type(8)))  short s16x8;   // 8 bf16 = 4 VGPR (MFMA A/B frag)
typedef __attribute__((ext_vector_type(16))) float f32x16;  // MFMA C/D frag

__device__ __forceinline__ short bfbits(float x) {
    union { __hip_bfloat16 b; unsigned short u; } cv;
    cv.b = __float2bfloat16(x);
    return (short)cv.u;
}
__device__ __forceinline__ float bfval(float x) {
    return __bfloat162float(__float2bfloat16(x));
}

// Slot plan (K=16), P = -2 q.c + rq + rc  (validated R7-R11, absmax 0):
//  k0..3: x: FA=(mxh,mxh,mxl,mxl) FB=(xh,xl,xh,xl); k4..7: y; k8..11: z
//  k12,13: FA=(rqh,rql) FB=(1,1);  k14,15: FA=(1,1) FB=(rch,rcl)

__global__ __launch_bounds__(THREADS) void chamfer_pre(const float* __restrict__ preds,
                                                       s16x8* __restrict__ FBv,
                                                       unsigned int* __restrict__ wsmin,
                                                       unsigned long long* __restrict__ acc) {
    int i = blockIdx.x * THREADS + threadIdx.x;    // 0..65535
    wsmin[i] = INF_BITS;
    if (i == 0) { acc[0] = 0ull; acc[1] = 0ull; }
    if (i < NSIDE) {                               // preds records only (B side)
        float x = preds[3*i], y = preds[3*i+1], z = preds[3*i+2];
        float rq = fmaf(x, x, fmaf(y, y, z*z));
        float xh = bfval(x), yh = bfval(y), zh = bfval(z), rh = bfval(rq);
        const short one = (short)0x3F80;
        s16x8 lo, hi;
        lo[0] = bfbits(xh);     lo[1] = bfbits(x - xh);
        lo[2] = lo[0];          lo[3] = lo[1];
        lo[4] = bfbits(yh);     lo[5] = bfbits(y - yh);
        lo[6] = lo[4];          lo[7] = lo[5];
        hi[0] = bfbits(zh);     hi[1] = bfbits(z - zh);
        hi[2] = hi[0];          hi[3] = hi[1];
        hi[4] = one;            hi[5] = one;
        hi[6] = bfbits(rh);     hi[7] = bfbits(rq - rh);
        FBv[2*(size_t)i]     = lo;
        FBv[2*(size_t)i + 1] = hi;
    }
}

// A-frag for one gts row — identical math to R7-R11.
__device__ __forceinline__ s16x8 make_afrag(const float* __restrict__ Q, int row, int h) {
    const short one = (short)0x3F80;
    float x = Q[3*row], y = Q[3*row+1], z = Q[3*row+2];
    float rq = fmaf(x, x, fmaf(y, y, z*z));
    float xh = bfval(x), yh = bfval(y), zh = bfval(z), rh = bfval(rq);
    s16x8 r;
    if (h == 0) {
        short mh = bfbits(-2.f*xh), ml = bfbits(-2.f*(x - xh));
        short nh = bfbits(-2.f*yh), nl = bfbits(-2.f*(y - yh));
        r[0]=mh; r[1]=mh; r[2]=ml; r[3]=ml;
        r[4]=nh; r[5]=nh; r[6]=nl; r[7]=nl;
    } else {
        short mh = bfbits(-2.f*zh), ml = bfbits(-2.f*(z - zh));
        r[0]=mh; r[1]=mh; r[2]=ml; r[3]=ml;
        r[4]=bfbits(rh); r[5]=bfbits(rq - rh); r[6]=one; r[7]=one;
    }
    return r;
}

__device__ __forceinline__ float min16(const f32x16& d) {
    float a = fminf(fminf(d[0], d[1]), fminf(d[2], d[3]));
    float b = fminf(fminf(d[4], d[5]), fminf(d[6], d[7]));
    float c = fminf(fminf(d[8], d[9]), fminf(d[10], d[11]));
    float e = fminf(fminf(d[12], d[13]), fminf(d[14], d[15]));
    return fminf(fminf(a, b), fminf(c, e));
}

// Shared-P, occupancy-first: 1 strip/wave (32 gts rows), 1024 pred cols/block, 4-wave blocks.
__global__ __launch_bounds__(THREADS, 6) void chamfer_mfma(const float* __restrict__ gts,
                                                           const s16x8* __restrict__ FBv,
                                                           unsigned int* __restrict__ wsmin) {
    const int rbk = blockIdx.x;        // 0..63: 128 gts rows
    const int cb  = blockIdx.y;        // 0..7 : 1024 pred cols
    const int b   = blockIdx.z;

    const int t = threadIdx.x, lane = t & 63, wid = t >> 6;   // wid 0..3
    const int li = lane & 31, h = lane >> 5;                  // h: k-half

    const float* __restrict__ Q = gts + (size_t)b * NPTS * 3;
    const s16x8* __restrict__ FBb = FBv + 2ull * ((size_t)b * NPTS + (size_t)cb * 1024);
    const s16x8* __restrict__ Bp  = FBb + 2*li + h;

    __shared__ float colbuf[4][1024];  // per-wave col-min partials (plain writes)

    const int row0 = rbk * 128 + wid * 32 + li;
    const s16x8 a0 = make_afrag(Q, row0, h);

    f32x16 zero = {};
    float rmin[16];
    #pragma unroll
    for (int r = 0; r < 16; ++r) rmin[r] = INFINITY;

    // 1024 cols = 16 jp x 2 tiles; sequential folds (<=1 D-frag live); 1-deep prefetch
    s16x8 c0 = Bp[0], c1 = Bp[64];
    #pragma unroll 1
    for (int jp = 0; jp < 16; ++jp) {
        const int nj = (jp + 1) & 15;                        // wrap: in-bounds, no branch
        s16x8 f0 = Bp[(size_t)nj * 128], f1 = Bp[(size_t)nj * 128 + 64];

        __builtin_amdgcn_s_setprio(1);
        f32x16 d = __builtin_amdgcn_mfma_f32_32x32x16_bf16(a0, c0, zero, 0, 0, 0);
        __builtin_amdgcn_s_setprio(0);
        #pragma unroll
        for (int r = 0; r < 16; ++r) rmin[r] = fminf(rmin[r], d[r]);
        float cmA = min16(d);

        __builtin_amdgcn_s_setprio(1);
        d = __builtin_amdgcn_mfma_f32_32x32x16_bf16(a0, c1, zero, 0, 0, 0);
        __builtin_amdgcn_s_setprio(0);
        #pragma unroll
        for (int r = 0; r < 16; ++r) rmin[r] = fminf(rmin[r], d[r]);
        float cmB = min16(d);

        cmA = fminf(cmA, __shfl_xor(cmA, 32, 64));           // merge k-halves (col = li)
        cmB = fminf(cmB, __shfl_xor(cmB, 32, 64));
        if (h == 0) {
            colbuf[wid][jp * 64 + li]      = cmA;
            colbuf[wid][jp * 64 + 32 + li] = cmB;
        }
        c0 = f0; c1 = f1;
    }

    // row epilogue: per-gt mins (mins2 half)
    unsigned int* __restrict__ wrow = wsmin + NSIDE + (size_t)b * NPTS;
    #pragma unroll
    for (int r = 0; r < 16; ++r) {
        float m = rmin[r];
        #pragma unroll
        for (int off = 1; off <= 16; off <<= 1) m = fminf(m, __shfl_xor(m, off, 64));
        if (li == 0) {
            int rowin = (r & 3) + 8 * (r >> 2) + 4 * h;      // C/D row map (validated R7-R11)
            atomicMin(&wrow[rbk * 128 + wid * 32 + rowin], __float_as_uint(fmaxf(m, 0.f)));
        }
    }

    // col epilogue: per-pred mins (mins1 half); combine 4 waves via LDS, 1 atomic/col
    __syncthreads();
    unsigned int* __restrict__ wcol = wsmin + (size_t)b * NPTS;
    #pragma unroll
    for (int c = t; c < 1024; c += THREADS) {
        float v = fminf(fminf(colbuf[0][c], colbuf[1][c]),
                        fminf(colbuf[2][c], colbuf[3][c]));
        atomicMin(&wcol[cb * 1024 + c], __float_as_uint(fmaxf(v, 0.f)));
    }
}

__device__ __forceinline__ unsigned long long fixpt(unsigned int u) {
    return (unsigned long long)((double)__uint_as_float(u) * 4294967296.0);
}

// Deterministic multi-block reduce: exact u64 fixed-point atomics; last block writes out.
__global__ __launch_bounds__(THREADS) void chamfer_reduce(const unsigned int* __restrict__ wsmin,
                                                          unsigned long long* __restrict__ acc,
                                                          float* __restrict__ out) {
    const uint4* __restrict__ v = (const uint4*)wsmin;
    int i = blockIdx.x * THREADS + threadIdx.x;              // 64 blocks x 256 -> one uint4 each
    uint4 a = v[i];
    unsigned long long s = fixpt(a.x) + fixpt(a.y) + fixpt(a.z) + fixpt(a.w);
    for (int off = 32; off; off >>= 1) s += __shfl_down(s, off, 64);
    __shared__ unsigned long long sm[THREADS / 64];
    if ((threadIdx.x & 63) == 0) sm[threadIdx.x >> 6] = s;
    __syncthreads();
    if (threadIdx.x == 0) {
        unsigned long long bt = sm[0] + sm[1] + sm[2] + sm[3];
        atomicAdd(&acc[0], bt);
        __threadfence();
        unsigned long long old = atomicAdd(&acc[1], 1ull);
        if (old == 63ull) {
            unsigned long long tot = atomicAdd(&acc[0], 0ull);   // all adds visible
            out[0] = (float)((double)tot * (1.0 / 4294967296.0) * (1.0 / 8192.0));
        }
    }
}

extern "C" void kernel_launch(void* const* d_in, const int* in_sizes, int n_in,
                              void* d_out, int out_size, void* d_ws, size_t ws_size,
                              hipStream_t stream) {
    const float* preds = (const float*)d_in[0];
    const float* gts   = (const float*)d_in[1];
    float* out = (float*)d_out;
    s16x8* FBv = (s16x8*)d_ws;
    unsigned int* wsmin = (unsigned int*)((char*)d_ws + WS_MIN_OFF);
    unsigned long long* acc = (unsigned long long*)((char*)d_ws + WS_ACC_OFF);

    chamfer_pre<<<NMINS / THREADS, THREADS, 0, stream>>>(preds, FBv, wsmin, acc);

    dim3 grid(64, 8, BATCH);   // 128-row blocks x 1024-col blocks x batch
    chamfer_mfma<<<grid, THREADS, 0, stream>>>(gts, FBv, wsmin);

    chamfer_reduce<<<NMINS / 4 / THREADS, THREADS, 0, stream>>>(wsmin, acc, out);
}